// Round 8
// baseline (220.413 us; speedup 1.0000x reference)
//
#include <hip/hip_runtime.h>
#include <math.h>

typedef float v2f __attribute__((ext_vector_type(2)));

namespace {

constexpr int C_DIM = 4;
constexpr int D_DIM = 64;
constexpr int H_DIM = 160;
constexpr int W_DIM = 160;

constexpr int TH = 20;
constexpr int TW = 20;
constexpr int HALO = 5;
constexpr int EH = 30;
constexpr int EW = 30;
constexpr int XST = 31;          // v2f stride of xy rows (odd; col 30 = pad)
constexpr int MST = 21;          // float4 stride of mid rows (col 20 = pad)
constexpr int NPIX = EH * EW;    // 900

constexpr int TILES_W = 8;       // 160/20
constexpr int TPC = 64;          // 8x8 tiles per (b,c)
constexpr int NBLOCKS = 2 * C_DIM * TPC;  // 512 = exactly 2 blocks/CU

constexpr float C1f = 1e-4f;
constexpr float C2f = 9e-4f;
constexpr float INV_N = 1.0f / (2.0f * 64.0f * 160.0f * 160.0f);

struct GW { float g[11]; };

}  // namespace

__global__ void finalize_kernel(const float* __restrict__ partial,
                                float* __restrict__ out) {
    const int tid = threadIdx.x;
    const int c = tid >> 6;        // one wave per channel
    const int lane = tid & 63;     // lane == tile index (TPC == 64)
    float s = partial[c * TPC + lane] +
              partial[C_DIM * TPC + c * TPC + lane];
#pragma unroll
    for (int off = 32; off > 0; off >>= 1) s += __shfl_down(s, off, 64);
    if (lane == 0 && c < C_DIM) out[c] = 1.0f - s * INV_N;
}

__global__ __launch_bounds__(256, 2) void ssim3d_kernel(
    const float* __restrict__ img1, const float* __restrict__ img2,
    float* __restrict__ partial, GW gwp) {

    const int bid = blockIdx.x;
    const int tile = bid % TPC;
    const int c = (bid / TPC) % C_DIM;
    const int b = bid / (TPC * C_DIM);
    const int h0 = (tile / TILES_W) * TH;
    const int w0 = (tile % TILES_W) * TW;

    const long planeHW = (long)H_DIM * W_DIM;
    const long volbase = (long)(b * C_DIM + c) * D_DIM * planeHW;
    const long org = volbase + (long)(h0 - HALO) * W_DIM + (w0 - HALO);
    const float* __restrict__ p1 = img1 + org;
    const float* __restrict__ p2 = img2 + org;

    const bool interior = (h0 >= HALO) && (h0 + TH + HALO <= H_DIM) &&
                          (w0 >= HALO) && (w0 + TW + HALO <= W_DIM);

    // ---- LDS (both stages double-buffered -> 1 barrier per slice) ----
    __shared__ v2f    xy[2][EH][XST];    // interleaved (x,y), b64
    __shared__ float4 mid[2][EH][MST];   // W-conv (sx,sy | sq,sp), b128
    __shared__ float  rbuf[4];

    const int tid = threadIdx.x;

    // ---- staging decode (4 positions/thread, 900 px) ----
    int hh_[4], ww_[4], off_[4];
    bool live_[4], ok_[4];
#pragma unroll
    for (int k = 0; k < 4; ++k) {
        const int e = tid + k * 256;
        live_[k] = (e < NPIX);
        const int hh = e / EW;
        const int ww = e - hh * EW;
        hh_[k] = hh; ww_[k] = ww;
        off_[k] = hh * W_DIM + ww;
        const int gh = h0 - HALO + hh;
        const int gw = w0 - HALO + ww;
        ok_[k] = ((unsigned)gh < (unsigned)H_DIM) &&
                 ((unsigned)gw < (unsigned)W_DIM);
    }

    auto fetch_slice = [&](int s, v2f lv[4]) {
        const long sb = (long)s * planeHW;
#pragma unroll
        for (int k = 0; k < 4; ++k) {
            lv[k] = (v2f){0.0f, 0.0f};
            if (live_[k] && (interior || ok_[k])) {
                const long gi = sb + off_[k];
                lv[k].x = p1[gi];
                lv[k].y = p2[gi];
            }
        }
    };
    auto commit_slice = [&](int buf, const v2f lv[4]) {
#pragma unroll
        for (int k = 0; k < 4; ++k)
            if (live_[k]) xy[buf][hh_[k]][ww_[k]] = lv[k];
    };

    // ---- wconv: 210 workers (rows fastest), 3 outputs each, 13-tap stream.
    // Group 6 (cols 18,19) computes a third output into pad col 20 of mid
    // (and reads pad col 30 of xy): write-only garbage, never consumed.
    const bool wactive = (tid < 210);
    const int whh = tid % 30;
    const int wg  = (tid / 30) * 3;   // 0,3,..,18

    auto wconv = [&](int cur) {
        v2f a0 = {0.f,0.f}, a1 = {0.f,0.f}, a2 = {0.f,0.f};
        v2f q0 = {0.f,0.f}, q1 = {0.f,0.f}, q2 = {0.f,0.f};
#pragma unroll
        for (int t = 0; t < 13; ++t) {
            const v2f xv = xy[cur][whh][wg + t];
            v2f qp;
            qp.x = fmaf(xv.x, xv.x, xv.y * xv.y);  // x^2 + y^2
            qp.y = xv.x * xv.y;                    // x*y
            if (t <= 10) {
                const v2f g2 = {gwp.g[t], gwp.g[t]};
                a0 = __builtin_elementwise_fma(g2, xv, a0);
                q0 = __builtin_elementwise_fma(g2, qp, q0);
            }
            if (t >= 1 && t <= 11) {
                const v2f g2 = {gwp.g[t-1], gwp.g[t-1]};
                a1 = __builtin_elementwise_fma(g2, xv, a1);
                q1 = __builtin_elementwise_fma(g2, qp, q1);
            }
            if (t >= 2) {
                const v2f g2 = {gwp.g[t-2], gwp.g[t-2]};
                a2 = __builtin_elementwise_fma(g2, xv, a2);
                q2 = __builtin_elementwise_fma(g2, qp, q2);
            }
        }
        mid[cur][whh][wg]     = make_float4(a0.x, a0.y, q0.x, q0.y);
        mid[cur][whh][wg + 1] = make_float4(a1.x, a1.y, q1.x, q1.y);
        mid[cur][whh][wg + 2] = make_float4(a2.x, a2.y, q2.x, q2.y);
    };

    // ---- hconv: 200 workers, 2 H-outputs each (rows h, h+1), 12-tap stream
    const bool hworker = (tid < 200);
    const int hw = tid % 20;          // w position
    const int hb = (tid / 20) * 2;    // h base: 0,2,..,18

    float accum = 0.0f;
    auto ssim_add = [&](v2f mxy, v2f mqp) {
        const float m1 = mxy.x, m2 = mxy.y;
        const float q = mqp.x, pp = mqp.y;
        const float m1s = m1 * m1;
        const float m2s = m2 * m2;
        const float m12 = m1 * m2;
        const float spp = q - m1s - m2s;
        const float s12 = pp - m12;
        const float num = (2.0f * m12 + C1f) * (2.0f * s12 + C2f);
        const float den = (m1s + m2s + C1f) * (spp + C2f);
        accum = fmaf(num, __builtin_amdgcn_rcpf(den), accum);
    };

    // two D-windows (outputs h=hb, hb+1): 14 slots, insert at 10+u, consume
    // over [u..u+10], shift by 4 per 4 slices. Static indices only.
    v2f w0xy[14], w0qp[14], w1xy[14], w1qp[14];
#pragma unroll
    for (int i = 0; i < 14; ++i) {
        w0xy[i] = (v2f){0.f, 0.f}; w0qp[i] = (v2f){0.f, 0.f};
        w1xy[i] = (v2f){0.f, 0.f}; w1qp[i] = (v2f){0.f, 0.f};
    }

    // ---- prologue: commit slice 0, prefetch slice 1 (distance-2 pipeline)
    v2f lvA[4], lvB[4];
    {
        fetch_slice(0, lvA);
        commit_slice(0, lvA);
        fetch_slice(1, lvA);   // lvA holds slice 1 entering phase 0 (u=0 even)
    }
    __syncthreads();

    for (int sb = 0; sb < D_DIM; sb += 4) {   // sb mult of 4 -> s&1 == u&1
#pragma unroll
        for (int u = 0; u < 4; ++u) {
            const int s = sb + u;
            // issue prefetch for s+2; commit s+1 (fetched one phase ago:
            // its latency is fully covered -> no vmcnt stall at commit)
            if ((u & 1) == 0) {
                if (s + 2 < D_DIM) fetch_slice(s + 2, lvB);
                if (s + 1 < D_DIM) commit_slice((s + 1) & 1, lvA);
            } else {
                if (s + 2 < D_DIM) fetch_slice(s + 2, lvA);
                if (s + 1 < D_DIM) commit_slice((s + 1) & 1, lvB);
            }
            if (wactive) wconv(u & 1);
            __syncthreads();
            if (hworker) {
                // H-conv, 2 outputs from 12 b128 reads
                v2f z0x = {0.f,0.f}, z0q = {0.f,0.f};
                v2f z1x = {0.f,0.f}, z1q = {0.f,0.f};
#pragma unroll
                for (int t = 0; t < 12; ++t) {
                    const float4 m = mid[u & 1][hb + t][hw];
                    const v2f ma = {m.x, m.y};
                    const v2f mb = {m.z, m.w};
                    if (t <= 10) {
                        const v2f g2 = {gwp.g[t], gwp.g[t]};
                        z0x = __builtin_elementwise_fma(g2, ma, z0x);
                        z0q = __builtin_elementwise_fma(g2, mb, z0q);
                    }
                    if (t >= 1) {
                        const v2f g2 = {gwp.g[t-1], gwp.g[t-1]};
                        z1x = __builtin_elementwise_fma(g2, ma, z1x);
                        z1q = __builtin_elementwise_fma(g2, mb, z1q);
                    }
                }
                w0xy[10 + u] = z0x; w0qp[10 + u] = z0q;
                w1xy[10 + u] = z1x; w1qp[10 + u] = z1q;
                if (s >= HALO) {   // output d = s-5
                    v2f mx0 = {0.f,0.f}, mq0 = {0.f,0.f};
                    v2f mx1 = {0.f,0.f}, mq1 = {0.f,0.f};
#pragma unroll
                    for (int t = 0; t < 11; ++t) {
                        const v2f g2 = {gwp.g[t], gwp.g[t]};
                        mx0 = __builtin_elementwise_fma(g2, w0xy[u + t], mx0);
                        mq0 = __builtin_elementwise_fma(g2, w0qp[u + t], mq0);
                        mx1 = __builtin_elementwise_fma(g2, w1xy[u + t], mx1);
                        mq1 = __builtin_elementwise_fma(g2, w1qp[u + t], mq1);
                    }
                    ssim_add(mx0, mq0);
                    ssim_add(mx1, mq1);
                }
            }
        }
        if (hworker) {
            // shift both windows by 4
#pragma unroll
            for (int k = 0; k < 10; ++k) {
                w0xy[k] = w0xy[k + 4]; w0qp[k] = w0qp[k + 4];
                w1xy[k] = w1xy[k + 4]; w1qp[k] = w1qp[k + 4];
            }
        }
    }

    // epilogue: outputs d = 59..63; windows hold slices 54+k at slot k (0..9)
    if (hworker) {
#pragma unroll
        for (int i = 10; i < 14; ++i) {
            w0xy[i] = (v2f){0.f, 0.f}; w0qp[i] = (v2f){0.f, 0.f};
            w1xy[i] = (v2f){0.f, 0.f}; w1qp[i] = (v2f){0.f, 0.f};
        }
#pragma unroll
        for (int u2 = 0; u2 < 5; ++u2) {   // output d = 59 + u2
            v2f mx0 = {0.f,0.f}, mq0 = {0.f,0.f};
            v2f mx1 = {0.f,0.f}, mq1 = {0.f,0.f};
#pragma unroll
            for (int t = 0; t < 11; ++t) {
                if (u2 + t <= 13) {        // static guard; dropped taps zero
                    const v2f g2 = {gwp.g[t], gwp.g[t]};
                    mx0 = __builtin_elementwise_fma(g2, w0xy[u2 + t], mx0);
                    mq0 = __builtin_elementwise_fma(g2, w0qp[u2 + t], mq0);
                    mx1 = __builtin_elementwise_fma(g2, w1xy[u2 + t], mx1);
                    mq1 = __builtin_elementwise_fma(g2, w1qp[u2 + t], mq1);
                }
            }
            ssim_add(mx0, mq0);
            ssim_add(mx1, mq1);
        }
    }

    // ---- block reduction -> one partial per block ----
#pragma unroll
    for (int off = 32; off > 0; off >>= 1) accum += __shfl_down(accum, off, 64);
    const int wave = tid >> 6;
    const int lane = tid & 63;
    if (lane == 0) rbuf[wave] = accum;
    __syncthreads();
    if (tid == 0) partial[bid] = rbuf[0] + rbuf[1] + rbuf[2] + rbuf[3];
}

extern "C" void kernel_launch(void* const* d_in, const int* in_sizes, int n_in,
                              void* d_out, int out_size, void* d_ws, size_t ws_size,
                              hipStream_t stream) {
    const float* img1 = (const float*)d_in[0];
    const float* img2 = (const float*)d_in[1];
    float* out = (float*)d_out;
    float* partial = (float*)d_ws;   // NBLOCKS floats

    GW gw;
    {
        double gd[11];
        double ssum = 0.0;
        for (int i = 0; i < 11; ++i) {
            const double t = (double)(i - 5);
            gd[i] = exp(-(t * t) / 4.5);
            ssum += gd[i];
        }
        for (int i = 0; i < 11; ++i) gw.g[i] = (float)(gd[i] / ssum);
    }

    ssim3d_kernel<<<NBLOCKS, 256, 0, stream>>>(img1, img2, partial, gw);
    finalize_kernel<<<1, 256, 0, stream>>>(partial, out);
}